// Round 1
// baseline (24.147 us; speedup 1.0000x reference)
//
#include <hip/hip_runtime.h>

#define NUM_BINS 256
#define NBATCH 8
#define N_PER_BATCH (3 * 256 * 256)              // 196608 elements per batch
#define BLOCKS_PER_BATCH 32
#define CHUNK (N_PER_BATCH / BLOCKS_PER_BATCH)   // 6144 elements per block
#define THREADS 256
#define VEC_PER_THREAD (CHUNK / (THREADS * 4))   // 6 float4 loads per thread

// ---------------------------------------------------------------------------
// Kernel 1: per-block partial histograms.
// grid = NBATCH * BLOCKS_PER_BATCH blocks, 256 threads each.
// Each block processes CHUNK contiguous elements of one batch via float4
// loads, scatters into per-wave-replicated LDS histograms (reduces LDS atomic
// contention 4x), then writes a 256-bin partial to workspace.
// ---------------------------------------------------------------------------
__global__ __launch_bounds__(THREADS)
void hist_partial(const float* __restrict__ img, float* __restrict__ partial) {
    __shared__ float h[4][NUM_BINS];
    const int tid  = threadIdx.x;
    const int wave = tid >> 6;

    // zero LDS (tid spans 0..255 == NUM_BINS)
    #pragma unroll
    for (int w = 0; w < 4; ++w) h[w][tid] = 0.0f;
    __syncthreads();

    const int blk = blockIdx.x;
    const int b   = blk / BLOCKS_PER_BATCH;
    const int c   = blk % BLOCKS_PER_BATCH;
    const float4* __restrict__ src =
        (const float4*)(img + (size_t)b * N_PER_BATCH + (size_t)c * CHUNK);
    float* hw = h[wave];

    #pragma unroll
    for (int i = 0; i < VEC_PER_THREAD; ++i) {
        float4 v = src[i * THREADS + tid];
        float vals[4] = {v.x, v.y, v.z, v.w};
        #pragma unroll
        for (int j = 0; j < 4; ++j) {
            float t = vals[j] * 255.0f;               // x / bin_width
            t = fminf(fmaxf(t, 0.0f), 255.0f);        // robustness clamp
            int k = (int)t;
            if (k > 254) k = 254;                     // t==255 -> all weight to bin 255
            float f = t - (float)k;                   // weight for bin k+1
            atomicAdd(&hw[k],     1.0f - f);
            atomicAdd(&hw[k + 1], f);
        }
    }
    __syncthreads();

    // fold the 4 wave-copies and emit this block's partial histogram
    float s = h[0][tid] + h[1][tid] + h[2][tid] + h[3][tid];
    partial[(size_t)blk * NUM_BINS + tid] = s;
}

// ---------------------------------------------------------------------------
// Kernel 2: reduce partials -> d_out. grid = NBATCH blocks x 256 threads.
// Deterministic (fixed summation order), overwrites d_out (no pre-zero needed).
// ---------------------------------------------------------------------------
__global__ __launch_bounds__(THREADS)
void hist_reduce(const float* __restrict__ partial, float* __restrict__ out) {
    const int bin = threadIdx.x;
    const int b   = blockIdx.x;
    const float* p = partial + (size_t)b * BLOCKS_PER_BATCH * NUM_BINS + bin;
    float s = 0.0f;
    #pragma unroll
    for (int c = 0; c < BLOCKS_PER_BATCH; ++c) s += p[(size_t)c * NUM_BINS];
    out[(size_t)b * NUM_BINS + bin] = s;
}

// ---------------------------------------------------------------------------
// Fallback (only if ws_size is too small): global-atomic histogram after an
// async memset of d_out. Same math, nondeterministic fp ordering (still well
// under threshold).
// ---------------------------------------------------------------------------
__global__ __launch_bounds__(THREADS)
void hist_atomic(const float* __restrict__ img, float* __restrict__ out) {
    __shared__ float h[4][NUM_BINS];
    const int tid  = threadIdx.x;
    const int wave = tid >> 6;
    #pragma unroll
    for (int w = 0; w < 4; ++w) h[w][tid] = 0.0f;
    __syncthreads();

    const int blk = blockIdx.x;
    const int b   = blk / BLOCKS_PER_BATCH;
    const int c   = blk % BLOCKS_PER_BATCH;
    const float4* __restrict__ src =
        (const float4*)(img + (size_t)b * N_PER_BATCH + (size_t)c * CHUNK);
    float* hw = h[wave];

    #pragma unroll
    for (int i = 0; i < VEC_PER_THREAD; ++i) {
        float4 v = src[i * THREADS + tid];
        float vals[4] = {v.x, v.y, v.z, v.w};
        #pragma unroll
        for (int j = 0; j < 4; ++j) {
            float t = vals[j] * 255.0f;
            t = fminf(fmaxf(t, 0.0f), 255.0f);
            int k = (int)t;
            if (k > 254) k = 254;
            float f = t - (float)k;
            atomicAdd(&hw[k],     1.0f - f);
            atomicAdd(&hw[k + 1], f);
        }
    }
    __syncthreads();
    float s = h[0][tid] + h[1][tid] + h[2][tid] + h[3][tid];
    atomicAdd(&out[(size_t)b * NUM_BINS + tid], s);
}

extern "C" void kernel_launch(void* const* d_in, const int* in_sizes, int n_in,
                              void* d_out, int out_size, void* d_ws, size_t ws_size,
                              hipStream_t stream) {
    const float* img = (const float*)d_in[0];   // (8,3,256,256) f32
    float* out = (float*)d_out;                 // (8,256) f32

    const size_t ws_needed = (size_t)NBATCH * BLOCKS_PER_BATCH * NUM_BINS * sizeof(float);
    if (ws_size >= ws_needed) {
        float* partial = (float*)d_ws;
        hist_partial<<<NBATCH * BLOCKS_PER_BATCH, THREADS, 0, stream>>>(img, partial);
        hist_reduce<<<NBATCH, THREADS, 0, stream>>>(partial, out);
    } else {
        hipMemsetAsync(d_out, 0, (size_t)out_size * sizeof(float), stream);
        hist_atomic<<<NBATCH * BLOCKS_PER_BATCH, THREADS, 0, stream>>>(img, out);
    }
}